// Round 15
// baseline (1675.364 us; speedup 1.0000x reference)
//
#include <hip/hip_runtime.h>

typedef _Float16 h2_t __attribute__((ext_vector_type(2)));
typedef _Float16 h4_t __attribute__((ext_vector_type(4)));
typedef _Float16 h8_t __attribute__((ext_vector_type(8)));
typedef float    f4_t __attribute__((ext_vector_type(4)));

#define B_  64
#define T_  512
#define F_  128
#define H_  512

static __device__ __forceinline__ float fdot2f(h2_t a, h2_t b, float c) {
#if __has_builtin(__builtin_amdgcn_fdot2)
    return __builtin_amdgcn_fdot2(a, b, c, false);
#else
    return c + (float)a.x * (float)b.x + (float)a.y * (float)b.y;
#endif
}

static __device__ __forceinline__ void dot8(float& acc, uint4 w, uint4 h) {
    acc = fdot2f(__builtin_bit_cast(h2_t, w.x), __builtin_bit_cast(h2_t, h.x), acc);
    acc = fdot2f(__builtin_bit_cast(h2_t, w.y), __builtin_bit_cast(h2_t, h.y), acc);
    acc = fdot2f(__builtin_bit_cast(h2_t, w.z), __builtin_bit_cast(h2_t, h.z), acc);
    acc = fdot2f(__builtin_bit_cast(h2_t, w.w), __builtin_bit_cast(h2_t, h.w), acc);
}

// int8 dot helpers
static __device__ __forceinline__ int d4(int acc, unsigned a, unsigned b) {
#if __has_builtin(__builtin_amdgcn_sdot4)
    return __builtin_amdgcn_sdot4((int)a, (int)b, acc, false);
#else
    #pragma unroll
    for (int i = 0; i < 4; ++i)
        acc += (int)(signed char)((a >> (8 * i)) & 0xff) *
               (int)(signed char)((b >> (8 * i)) & 0xff);
    return acc;
#endif
}
static __device__ __forceinline__ int dot16i8(int acc, uint4 w, uint4 h) {
    acc = d4(acc, w.x, h.x);
    acc = d4(acc, w.y, h.y);
    acc = d4(acc, w.z, h.z);
    acc = d4(acc, w.w, h.w);
    return acc;
}

// ---------------- prep kernels ----------------
__global__ void k_cast_f16(const float* __restrict__ src, _Float16* __restrict__ dst, int n) {
    int i = blockIdx.x * blockDim.x + threadIdx.x;
    if (i < n) dst[i] = (_Float16)src[i];
}

// Wz[c][k] = Wih_de[c][512+k]  (z-contribution of the decoder input weight)
__global__ void k_prep_z(const float* __restrict__ Wih_de, _Float16* __restrict__ Wz) {
    int i = blockIdx.x * blockDim.x + threadIdx.x;   // over 512*512
    int cc = i >> 9, kk = i & 511;
    Wz[i] = (_Float16)Wih_de[cc * 1024 + 512 + kk];
}

__global__ void k_prep_bias(const float* __restrict__ a, const float* __restrict__ b,
                            float* __restrict__ o) {
    int i = threadIdx.x;
    o[i] = a[i] + b[i];
}

// per-row symmetric int8 quantization of W (optionally A+B elementwise).
__global__ void k_quant(const float* __restrict__ A, int sA,
                        const float* __restrict__ Bo, int sB,
                        signed char* __restrict__ q, float* __restrict__ fac) {
    __shared__ float red[128];
    const int c = blockIdx.x, t = threadIdx.x;
    f4_t v = *(const f4_t*)(A + (size_t)c * sA + t * 4);
    if (Bo) {
        f4_t vb = *(const f4_t*)(Bo + (size_t)c * sB + t * 4);
        v = v + vb;
    }
    float m = fmaxf(fmaxf(fabsf(v[0]), fabsf(v[1])), fmaxf(fabsf(v[2]), fabsf(v[3])));
    red[t] = m;
    __syncthreads();
    for (int o = 64; o; o >>= 1) {
        if (t < o) red[t] = fmaxf(red[t], red[t + o]);
        __syncthreads();
    }
    float mx = red[0];
    float inv = mx > 0.f ? 127.f / mx : 0.f;
    unsigned r = 0;
    #pragma unroll
    for (int i = 0; i < 4; ++i) {
        int qi = (int)rintf(fminf(fmaxf(v[i] * inv, -127.f), 127.f));
        r |= ((unsigned)(unsigned char)(signed char)qi) << (8 * i);
    }
    *(unsigned*)(q + (size_t)c * 512 + t * 4) = r;
    if (t == 0) fac[c] = mx > 0.f ? mx / 127.f : 0.f;
}

// ---------------- GEMM: C[M,N] = A[M,K] @ Bt[N,K]^T + bias[N] ----------------
#define BM 128
#define BN 128
#define BK 32
#define LDT 40   // padded LDS row stride in f16 units

__global__ __launch_bounds__(256) void k_gemm(
    const _Float16* __restrict__ A, const _Float16* __restrict__ Bt,
    const float* __restrict__ bias,
    float* __restrict__ Cf, _Float16* __restrict__ Ch,
    int M, int N, int K) {
    __shared__ _Float16 Al[BM * LDT];
    __shared__ _Float16 Bl[BN * LDT];
    const int tid = threadIdx.x;
    const int bm = blockIdx.x * BM, bn = blockIdx.y * BN;
    const int wid = tid >> 6, lane = tid & 63;
    const int wm = (wid >> 1) * 64, wn = (wid & 1) * 64;
    const int l15 = lane & 15, l4 = lane >> 4;

    f4_t acc[4][4];
    #pragma unroll
    for (int i = 0; i < 4; ++i)
        #pragma unroll
        for (int j = 0; j < 4; ++j) {
            f4_t zz = {0.f, 0.f, 0.f, 0.f};
            acc[i][j] = zz;
        }

    const int r = tid >> 1, hf = tid & 1;
    const h8_t* gA0 = (const h8_t*)(A + (size_t)(bm + r) * K);
    const h8_t* gB0 = (const h8_t*)(Bt + (size_t)(bn + r) * K);

    for (int k0 = 0; k0 < K; k0 += BK) {
        __syncthreads();
        int kf = (k0 >> 3) + hf * 2;
        h8_t a0 = gA0[kf], a1 = gA0[kf + 1];
        h8_t b0 = gB0[kf], b1 = gB0[kf + 1];
        *(h8_t*)&Al[r * LDT + hf * 16]     = a0;
        *(h8_t*)&Al[r * LDT + hf * 16 + 8] = a1;
        *(h8_t*)&Bl[r * LDT + hf * 16]     = b0;
        *(h8_t*)&Bl[r * LDT + hf * 16 + 8] = b1;
        __syncthreads();
        h8_t af[4], bf[4];
        #pragma unroll
        for (int i = 0; i < 4; ++i) af[i] = *(const h8_t*)&Al[(wm + i * 16 + l15) * LDT + l4 * 8];
        #pragma unroll
        for (int j = 0; j < 4; ++j) bf[j] = *(const h8_t*)&Bl[(wn + j * 16 + l15) * LDT + l4 * 8];
        #pragma unroll
        for (int i = 0; i < 4; ++i)
            #pragma unroll
            for (int j = 0; j < 4; ++j)
                acc[i][j] = __builtin_amdgcn_mfma_f32_16x16x32_f16(af[i], bf[j], acc[i][j], 0, 0, 0);
    }

    #pragma unroll
    for (int i = 0; i < 4; ++i) {
        int m0 = bm + wm + i * 16 + l4 * 4;
        #pragma unroll
        for (int j = 0; j < 4; ++j) {
            int n0 = bn + wn + j * 16 + l15;
            float bb = bias ? bias[n0] : 0.f;
            #pragma unroll
            for (int rr = 0; rr < 4; ++rr) {
                float v = acc[i][j][rr] + bb;
                size_t off = (size_t)(m0 + rr) * N + n0;
                if (Cf) Cf[off] = v;
                if (Ch) Ch[off] = (_Float16)v;
            }
        }
    }
}

// ---------------- persistent-weight RNN, int8, 1-row-per-thread ----------------
// Linear model from r11-r14: cyc = base(~1360) + 110*nWL + 30*nRestream; h
// broadcasts ~free. r12 (nWL=4) was optimal on the nWL/nR axis; this round cuts
// BASE: thread tid owns row tid over ALL K (same 512 MACs/thread):
//  * no ipart exchange (full dot in one thread),
//  * double-buffered h_q[2][512] -> ONE barrier/step (read buf t&1, write buf
//    (t+1)&1; end-of-step barrier separates iter-t reads from iter-t+1 writes),
//  * 4 independent accumulators (dependent sdot4 chain 64 -> 32 deep).
// Weights: 28 uint4 chunks claimed in VGPRs (allocator keeps ~17-20, restream
// of the rest costs ~30 cyc/chunk) + 4 chunks in WL per-lane LDS.
__global__ __launch_bounds__(512) void k_rnn(
    const signed char* __restrict__ Wq,   // [512][512] i8
    const float* __restrict__ fac,        // [512] weight dequant scale (max/127)
    const _Float16* __restrict__ pre,     // [B,T,H] f16 pre-activation
    _Float16* __restrict__ out) {         // [B,T,H] f16 hidden states
    __shared__ __align__(16) uint4 WL[4 * 512];           // 32 KiB weight LDS share
    __shared__ __align__(16) signed char h_q[2][H_];      // 1 KiB double buffer
    const int tid = threadIdx.x;
    const int b = blockIdx.x;

    // row `tid`, all K: 32 uint4 chunks
    const uint4* q = (const uint4*)(Wq + (size_t)tid * 512);
    uint4 wv[28];
    #pragma unroll
    for (int j = 0; j < 28; ++j) wv[j] = q[j];
    #pragma unroll
    for (int j = 0; j < 4; ++j) WL[j * 512 + tid] = q[28 + j];
    if (tid < 32) ((uint4*)&h_q[0][0])[tid] = make_uint4(0u, 0u, 0u, 0u);
    __syncthreads();

    const size_t base = (size_t)b * T_ * H_ + tid;
    float pcur = (float)pre[base];
    const float facr = fac[tid] * (1.f / 127.f);

    for (int t = 0; t < T_; ++t) {
        int tn = (t + 1 < T_) ? t + 1 : t;
        _Float16 pnx = pre[base + (size_t)tn * H_];

        const uint4* hv = (const uint4*)&h_q[t & 1][0];   // broadcast reads
        int a0 = 0, a1 = 0, a2 = 0, a3 = 0;               // 4-way chain split
        #pragma unroll
        for (int j = 0; j < 7; ++j) {
            a0 = dot16i8(a0, wv[4 * j + 0], hv[4 * j + 0]);
            a1 = dot16i8(a1, wv[4 * j + 1], hv[4 * j + 1]);
            a2 = dot16i8(a2, wv[4 * j + 2], hv[4 * j + 2]);
            a3 = dot16i8(a3, wv[4 * j + 3], hv[4 * j + 3]);
        }
        a0 = dot16i8(a0, WL[0 * 512 + tid], hv[28]);
        a1 = dot16i8(a1, WL[1 * 512 + tid], hv[29]);
        a2 = dot16i8(a2, WL[2 * 512 + tid], hv[30]);
        a3 = dot16i8(a3, WL[3 * 512 + tid], hv[31]);

        int tot = (a0 + a1) + (a2 + a3);
        float hn = tanhf((float)tot * facr + pcur);
        out[base + (size_t)t * H_] = (_Float16)hn;
        h_q[(t + 1) & 1][tid] = (signed char)(int)rintf(hn * 127.f);
        __syncthreads();
        pcur = (float)pnx;
    }
}

// ---------------- reparameterize: z = eps * exp(lv/2) + mu ----------------
__global__ void k_z(const float* __restrict__ mu, const float* __restrict__ lv,
                    const float* __restrict__ eps, _Float16* __restrict__ z, int n4) {
    int i = blockIdx.x * blockDim.x + threadIdx.x;
    if (i >= n4) return;
    f4_t m = ((const f4_t*)mu)[i];
    f4_t l = ((const f4_t*)lv)[i];
    f4_t e = ((const f4_t*)eps)[i];
    h4_t r;
    #pragma unroll
    for (int j = 0; j < 4; ++j) r[j] = (_Float16)(e[j] * expf(l[j] * 0.5f) + m[j]);
    ((h4_t*)z)[i] = r;
}

// ---------------- launch ----------------
extern "C" void kernel_launch(void* const* d_in, const int* in_sizes, int n_in,
                              void* d_out, int out_size, void* d_ws, size_t ws_size,
                              hipStream_t stream) {
    const float* x      = (const float*)d_in[0];
    const float* eps    = (const float*)d_in[1];
    const float* Wih_en = (const float*)d_in[2];
    const float* Whh_en = (const float*)d_in[3];
    const float* bih_en = (const float*)d_in[4];
    const float* bhh_en = (const float*)d_in[5];
    const float* W_mu   = (const float*)d_in[6];
    const float* b_mu   = (const float*)d_in[7];
    const float* W_lv   = (const float*)d_in[8];
    const float* b_lv   = (const float*)d_in[9];
    const float* Wih_de = (const float*)d_in[10];
    const float* Whh_de = (const float*)d_in[11];
    const float* bih_de = (const float*)d_in[12];
    const float* bhh_de = (const float*)d_in[13];
    const float* W_mux  = (const float*)d_in[14];
    const float* b_mux  = (const float*)d_in[15];
    const float* W_lvx  = (const float*)d_in[16];
    const float* b_lvx  = (const float*)d_in[17];
    float* out = (float*)d_out;

    char* ws = (char*)d_ws;
    _Float16* Wih_en_h = (_Float16*)(ws + 0);        // 512*128 f16
    _Float16* W_mu_h   = (_Float16*)(ws + 655360);
    _Float16* W_lv_h   = (_Float16*)(ws + 1179648);
    _Float16* Wz_h     = (_Float16*)(ws + 1703936);
    _Float16* Wmux_h   = (_Float16*)(ws + 2752512);  // 128*512
    _Float16* Wlvx_h   = (_Float16*)(ws + 2883584);
    float*    benc     = (float*)(ws + 3014656);     // 512 f32
    float*    bdec     = (float*)(ws + 3016704);
    signed char* Wq_en = (signed char*)(ws + 3018752);  // 512*512 i8
    signed char* Wq_de = (signed char*)(ws + 3280896);  // 512*512 i8
    float*    fac_en   = (float*)(ws + 3543040);     // 512 f32
    float*    fac_de   = (float*)(ws + 3545088);
    _Float16* x_h      = (_Float16*)(ws + 4194304);  // 64*512*128
    _Float16* pre_h    = (_Float16*)(ws + 12582912); // 64*512*512  (pre_en, then pre_de)
    _Float16* act_h    = (_Float16*)(ws + 46137344); // 64*512*512  (y, then decoder outputs)
    _Float16* z_h      = (_Float16*)(ws + 79691776); // 64*512*512

    const int thr = 256;
    k_cast_f16<<<(65536 + thr - 1) / thr, thr, 0, stream>>>(Wih_en, Wih_en_h, 65536);
    k_cast_f16<<<(262144 + thr - 1) / thr, thr, 0, stream>>>(W_mu, W_mu_h, 262144);
    k_cast_f16<<<(262144 + thr - 1) / thr, thr, 0, stream>>>(W_lv, W_lv_h, 262144);
    k_cast_f16<<<(65536 + thr - 1) / thr, thr, 0, stream>>>(W_mux, Wmux_h, 65536);
    k_cast_f16<<<(65536 + thr - 1) / thr, thr, 0, stream>>>(W_lvx, Wlvx_h, 65536);
    k_cast_f16<<<(4194304 + thr - 1) / thr, thr, 0, stream>>>(x, x_h, 4194304);
    k_prep_z<<<262144 / thr, thr, 0, stream>>>(Wih_de, Wz_h);
    k_prep_bias<<<1, 512, 0, stream>>>(bih_en, bhh_en, benc);
    k_prep_bias<<<1, 512, 0, stream>>>(bih_de, bhh_de, bdec);
    // int8 quantization of recurrent weights (per-row scales)
    k_quant<<<512, 128, 0, stream>>>(Whh_en, 512, nullptr, 0, Wq_en, fac_en);
    k_quant<<<512, 128, 0, stream>>>(Wih_de, 1024, Whh_de, 512, Wq_de, fac_de);

    dim3 gFull(32768 / BM, 512 / BN);   // 256 x 4
    dim3 gNarrow(32768 / BM, 1);        // 256 x 1 (N=128)

    // encoder pre-activation: x @ Wih_en^T + (bih_en + bhh_en)
    k_gemm<<<gFull, 256, 0, stream>>>(x_h, Wih_en_h, benc, nullptr, pre_h, 32768, 512, 128);
    // encoder recurrence -> y
    k_rnn<<<64, 512, 0, stream>>>(Wq_en, fac_en, pre_h, act_h);
    // mu_post, logsigma2_post
    k_gemm<<<gFull, 256, 0, stream>>>(act_h, W_mu_h, b_mu, out, nullptr, 32768, 512, 512);
    k_gemm<<<gFull, 256, 0, stream>>>(act_h, W_lv_h, b_lv, out + 16777216, nullptr, 32768, 512, 512);
    // z = eps * exp(lv/2) + mu
    k_z<<<4194304 / thr, thr, 0, stream>>>(out, out + 16777216, eps, z_h, 4194304);
    // decoder pre-activation: z @ Wz^T + (bih_de + bhh_de)
    k_gemm<<<gFull, 256, 0, stream>>>(z_h, Wz_h, bdec, nullptr, pre_h, 32768, 512, 512);
    // decoder recurrence -> outputs (reuse act_h; y is dead)
    k_rnn<<<64, 512, 0, stream>>>(Wq_de, fac_de, pre_h, act_h);
    // output projections
    k_gemm<<<gNarrow, 256, 0, stream>>>(act_h, Wmux_h, b_mux, out + 33554432, nullptr, 32768, 128, 512);
    k_gemm<<<gNarrow, 256, 0, stream>>>(act_h, Wlvx_h, b_lvx, out + 37748736, nullptr, 32768, 128, 512);
}

// Round 16
// 1108.406 us; speedup vs baseline: 1.5115x; 1.5115x over previous
//
#include <hip/hip_runtime.h>

typedef _Float16 h2_t __attribute__((ext_vector_type(2)));
typedef _Float16 h4_t __attribute__((ext_vector_type(4)));
typedef _Float16 h8_t __attribute__((ext_vector_type(8)));
typedef float    f4_t __attribute__((ext_vector_type(4)));

#define B_  64
#define T_  512
#define F_  128
#define H_  512

static __device__ __forceinline__ float fdot2f(h2_t a, h2_t b, float c) {
#if __has_builtin(__builtin_amdgcn_fdot2)
    return __builtin_amdgcn_fdot2(a, b, c, false);
#else
    return c + (float)a.x * (float)b.x + (float)a.y * (float)b.y;
#endif
}

static __device__ __forceinline__ void dot8(float& acc, uint4 w, uint4 h) {
    acc = fdot2f(__builtin_bit_cast(h2_t, w.x), __builtin_bit_cast(h2_t, h.x), acc);
    acc = fdot2f(__builtin_bit_cast(h2_t, w.y), __builtin_bit_cast(h2_t, h.y), acc);
    acc = fdot2f(__builtin_bit_cast(h2_t, w.z), __builtin_bit_cast(h2_t, h.z), acc);
    acc = fdot2f(__builtin_bit_cast(h2_t, w.w), __builtin_bit_cast(h2_t, h.w), acc);
}

// int8 dot helpers
static __device__ __forceinline__ int d4(int acc, unsigned a, unsigned b) {
#if __has_builtin(__builtin_amdgcn_sdot4)
    return __builtin_amdgcn_sdot4((int)a, (int)b, acc, false);
#else
    #pragma unroll
    for (int i = 0; i < 4; ++i)
        acc += (int)(signed char)((a >> (8 * i)) & 0xff) *
               (int)(signed char)((b >> (8 * i)) & 0xff);
    return acc;
#endif
}
static __device__ __forceinline__ int dot16i8(int acc, uint4 w, uint4 h) {
    acc = d4(acc, w.x, h.x);
    acc = d4(acc, w.y, h.y);
    acc = d4(acc, w.z, h.z);
    acc = d4(acc, w.w, h.w);
    return acc;
}

// ---------------- prep kernels ----------------
__global__ void k_cast_f16(const float* __restrict__ src, _Float16* __restrict__ dst, int n) {
    int i = blockIdx.x * blockDim.x + threadIdx.x;
    if (i < n) dst[i] = (_Float16)src[i];
}

// Wz[c][k] = Wih_de[c][512+k]  (z-contribution of the decoder input weight)
__global__ void k_prep_z(const float* __restrict__ Wih_de, _Float16* __restrict__ Wz) {
    int i = blockIdx.x * blockDim.x + threadIdx.x;   // over 512*512
    int cc = i >> 9, kk = i & 511;
    Wz[i] = (_Float16)Wih_de[cc * 1024 + 512 + kk];
}

__global__ void k_prep_bias(const float* __restrict__ a, const float* __restrict__ b,
                            float* __restrict__ o) {
    int i = threadIdx.x;
    o[i] = a[i] + b[i];
}

// per-row symmetric int8 quantization of W (optionally A+B elementwise).
__global__ void k_quant(const float* __restrict__ A, int sA,
                        const float* __restrict__ Bo, int sB,
                        signed char* __restrict__ q, float* __restrict__ fac) {
    __shared__ float red[128];
    const int c = blockIdx.x, t = threadIdx.x;
    f4_t v = *(const f4_t*)(A + (size_t)c * sA + t * 4);
    if (Bo) {
        f4_t vb = *(const f4_t*)(Bo + (size_t)c * sB + t * 4);
        v = v + vb;
    }
    float m = fmaxf(fmaxf(fabsf(v[0]), fabsf(v[1])), fmaxf(fabsf(v[2]), fabsf(v[3])));
    red[t] = m;
    __syncthreads();
    for (int o = 64; o; o >>= 1) {
        if (t < o) red[t] = fmaxf(red[t], red[t + o]);
        __syncthreads();
    }
    float mx = red[0];
    float inv = mx > 0.f ? 127.f / mx : 0.f;
    unsigned r = 0;
    #pragma unroll
    for (int i = 0; i < 4; ++i) {
        int qi = (int)rintf(fminf(fmaxf(v[i] * inv, -127.f), 127.f));
        r |= ((unsigned)(unsigned char)(signed char)qi) << (8 * i);
    }
    *(unsigned*)(q + (size_t)c * 512 + t * 4) = r;
    if (t == 0) fac[c] = mx > 0.f ? mx / 127.f : 0.f;
}

// ---------------- GEMM: C[M,N] = A[M,K] @ Bt[N,K]^T + bias[N] ----------------
#define BM 128
#define BN 128
#define BK 32
#define LDT 40   // padded LDS row stride in f16 units

__global__ __launch_bounds__(256) void k_gemm(
    const _Float16* __restrict__ A, const _Float16* __restrict__ Bt,
    const float* __restrict__ bias,
    float* __restrict__ Cf, _Float16* __restrict__ Ch,
    int M, int N, int K) {
    __shared__ _Float16 Al[BM * LDT];
    __shared__ _Float16 Bl[BN * LDT];
    const int tid = threadIdx.x;
    const int bm = blockIdx.x * BM, bn = blockIdx.y * BN;
    const int wid = tid >> 6, lane = tid & 63;
    const int wm = (wid >> 1) * 64, wn = (wid & 1) * 64;
    const int l15 = lane & 15, l4 = lane >> 4;

    f4_t acc[4][4];
    #pragma unroll
    for (int i = 0; i < 4; ++i)
        #pragma unroll
        for (int j = 0; j < 4; ++j) {
            f4_t zz = {0.f, 0.f, 0.f, 0.f};
            acc[i][j] = zz;
        }

    const int r = tid >> 1, hf = tid & 1;
    const h8_t* gA0 = (const h8_t*)(A + (size_t)(bm + r) * K);
    const h8_t* gB0 = (const h8_t*)(Bt + (size_t)(bn + r) * K);

    for (int k0 = 0; k0 < K; k0 += BK) {
        __syncthreads();
        int kf = (k0 >> 3) + hf * 2;
        h8_t a0 = gA0[kf], a1 = gA0[kf + 1];
        h8_t b0 = gB0[kf], b1 = gB0[kf + 1];
        *(h8_t*)&Al[r * LDT + hf * 16]     = a0;
        *(h8_t*)&Al[r * LDT + hf * 16 + 8] = a1;
        *(h8_t*)&Bl[r * LDT + hf * 16]     = b0;
        *(h8_t*)&Bl[r * LDT + hf * 16 + 8] = b1;
        __syncthreads();
        h8_t af[4], bf[4];
        #pragma unroll
        for (int i = 0; i < 4; ++i) af[i] = *(const h8_t*)&Al[(wm + i * 16 + l15) * LDT + l4 * 8];
        #pragma unroll
        for (int j = 0; j < 4; ++j) bf[j] = *(const h8_t*)&Bl[(wn + j * 16 + l15) * LDT + l4 * 8];
        #pragma unroll
        for (int i = 0; i < 4; ++i)
            #pragma unroll
            for (int j = 0; j < 4; ++j)
                acc[i][j] = __builtin_amdgcn_mfma_f32_16x16x32_f16(af[i], bf[j], acc[i][j], 0, 0, 0);
    }

    #pragma unroll
    for (int i = 0; i < 4; ++i) {
        int m0 = bm + wm + i * 16 + l4 * 4;
        #pragma unroll
        for (int j = 0; j < 4; ++j) {
            int n0 = bn + wn + j * 16 + l15;
            float bb = bias ? bias[n0] : 0.f;
            #pragma unroll
            for (int rr = 0; rr < 4; ++rr) {
                float v = acc[i][j][rr] + bb;
                size_t off = (size_t)(m0 + rr) * N + n0;
                if (Cf) Cf[off] = v;
                if (Ch) Ch[off] = (_Float16)v;
            }
        }
    }
}

// ---------------- persistent-weight RNN, int8, minimal-LDS-count ----------------
// Unified law from r11-r15: cyc ~ 11.5 x 8 waves x (LDS instrs/thread), counting
// EVERY LDS op (b128 or b32, broadcast or per-lane); L2 restream of non-resident
// weight chunks is hidden while its BW stays under the ~68 B/cyc/CU L2 link.
// r12 (16h + 4WL + 3 = 23 instr) = 2128 cyc. This round: nWL = 0 -- all 32
// chunks claimed in VGPRs (allocator keeps ~17, restreams ~15 = 61 B/cyc, just
// under the wall) -> 19 instr -> ~1850-2000 cyc/step.
// Layout (proven r12): thread (c2 = tid&255, s = tid>>8 wave-uniform) computes
// rows {c2, c2+256} over K-half s; symmetric finalize: thread tid finalizes
// row tid via one ipart write (tid^256) + one read.
__global__ __launch_bounds__(512) void k_rnn(
    const signed char* __restrict__ Wq,   // [512][512] i8
    const float* __restrict__ fac,        // [512] weight dequant scale (max/127)
    const _Float16* __restrict__ pre,     // [B,T,H] f16 pre-activation
    _Float16* __restrict__ out) {         // [B,T,H] f16 hidden states
    __shared__ __align__(16) signed char h_q[H_];         // h as i8 (512 B)
    __shared__ int ipart[H_];                             // 2 KiB int partials

    const int tid = threadIdx.x;
    const int c2 = tid & 255;
    const int s = tid >> 8;          // wave-uniform (waves 0-3: s=0, 4-7: s=1)
    const int b = blockIdx.x;

    // rows {c2, c2+256} over K-half [s*256, s*256+256): 16 uint4 chunks per row
    const uint4* q0 = (const uint4*)(Wq + (size_t)c2 * 512 + s * 256);
    const uint4* q1 = (const uint4*)(Wq + (size_t)(c2 + 256) * 512 + s * 256);
    uint4 wa[16], wb[16];
    #pragma unroll
    for (int j = 0; j < 16; ++j) { wa[j] = q0[j]; wb[j] = q1[j]; }
    if (tid < 32) ((uint4*)h_q)[tid] = make_uint4(0u, 0u, 0u, 0u);
    __syncthreads();

    // this thread finalizes row `tid`
    const size_t base = (size_t)b * T_ * H_ + tid;
    float pcur = (float)pre[base];
    const float facr = fac[tid] * (1.f / 127.f);

    for (int t = 0; t < T_; ++t) {
        int tn = (t + 1 < T_) ? t + 1 : t;
        _Float16 pnx = pre[base + (size_t)tn * H_];

        int i0 = 0, i1 = 0;   // partials for rows c2 / c2+256 over this K-half
        const uint4* hv = ((const uint4*)h_q) + s * 16;   // K-half of h (broadcast)
        #pragma unroll
        for (int j = 0; j < 16; ++j) {
            uint4 hh = hv[j];
            i0 = dot16i8(i0, wa[j], hh);
            i1 = dot16i8(i1, wb[j], hh);
        }

        // cross-half exchange: give the partner the partial for ITS row.
        ipart[tid ^ 256] = s ? i0 : i1;
        __syncthreads();
        int mine = s ? i1 : i0;
        float hn = tanhf((float)(mine + ipart[tid]) * facr + pcur);
        out[base + (size_t)t * H_] = (_Float16)hn;
        h_q[tid] = (signed char)(int)rintf(hn * 127.f);
        __syncthreads();
        pcur = (float)pnx;
    }
}

// ---------------- reparameterize: z = eps * exp(lv/2) + mu ----------------
__global__ void k_z(const float* __restrict__ mu, const float* __restrict__ lv,
                    const float* __restrict__ eps, _Float16* __restrict__ z, int n4) {
    int i = blockIdx.x * blockDim.x + threadIdx.x;
    if (i >= n4) return;
    f4_t m = ((const f4_t*)mu)[i];
    f4_t l = ((const f4_t*)lv)[i];
    f4_t e = ((const f4_t*)eps)[i];
    h4_t r;
    #pragma unroll
    for (int j = 0; j < 4; ++j) r[j] = (_Float16)(e[j] * expf(l[j] * 0.5f) + m[j]);
    ((h4_t*)z)[i] = r;
}

// ---------------- launch ----------------
extern "C" void kernel_launch(void* const* d_in, const int* in_sizes, int n_in,
                              void* d_out, int out_size, void* d_ws, size_t ws_size,
                              hipStream_t stream) {
    const float* x      = (const float*)d_in[0];
    const float* eps    = (const float*)d_in[1];
    const float* Wih_en = (const float*)d_in[2];
    const float* Whh_en = (const float*)d_in[3];
    const float* bih_en = (const float*)d_in[4];
    const float* bhh_en = (const float*)d_in[5];
    const float* W_mu   = (const float*)d_in[6];
    const float* b_mu   = (const float*)d_in[7];
    const float* W_lv   = (const float*)d_in[8];
    const float* b_lv   = (const float*)d_in[9];
    const float* Wih_de = (const float*)d_in[10];
    const float* Whh_de = (const float*)d_in[11];
    const float* bih_de = (const float*)d_in[12];
    const float* bhh_de = (const float*)d_in[13];
    const float* W_mux  = (const float*)d_in[14];
    const float* b_mux  = (const float*)d_in[15];
    const float* W_lvx  = (const float*)d_in[16];
    const float* b_lvx  = (const float*)d_in[17];
    float* out = (float*)d_out;

    char* ws = (char*)d_ws;
    _Float16* Wih_en_h = (_Float16*)(ws + 0);        // 512*128 f16
    _Float16* W_mu_h   = (_Float16*)(ws + 655360);
    _Float16* W_lv_h   = (_Float16*)(ws + 1179648);
    _Float16* Wz_h     = (_Float16*)(ws + 1703936);
    _Float16* Wmux_h   = (_Float16*)(ws + 2752512);  // 128*512
    _Float16* Wlvx_h   = (_Float16*)(ws + 2883584);
    float*    benc     = (float*)(ws + 3014656);     // 512 f32
    float*    bdec     = (float*)(ws + 3016704);
    signed char* Wq_en = (signed char*)(ws + 3018752);  // 512*512 i8
    signed char* Wq_de = (signed char*)(ws + 3280896);  // 512*512 i8
    float*    fac_en   = (float*)(ws + 3543040);     // 512 f32
    float*    fac_de   = (float*)(ws + 3545088);
    _Float16* x_h      = (_Float16*)(ws + 4194304);  // 64*512*128
    _Float16* pre_h    = (_Float16*)(ws + 12582912); // 64*512*512  (pre_en, then pre_de)
    _Float16* act_h    = (_Float16*)(ws + 46137344); // 64*512*512  (y, then decoder outputs)
    _Float16* z_h      = (_Float16*)(ws + 79691776); // 64*512*512

    const int thr = 256;
    k_cast_f16<<<(65536 + thr - 1) / thr, thr, 0, stream>>>(Wih_en, Wih_en_h, 65536);
    k_cast_f16<<<(262144 + thr - 1) / thr, thr, 0, stream>>>(W_mu, W_mu_h, 262144);
    k_cast_f16<<<(262144 + thr - 1) / thr, thr, 0, stream>>>(W_lv, W_lv_h, 262144);
    k_cast_f16<<<(65536 + thr - 1) / thr, thr, 0, stream>>>(W_mux, Wmux_h, 65536);
    k_cast_f16<<<(65536 + thr - 1) / thr, thr, 0, stream>>>(W_lvx, Wlvx_h, 65536);
    k_cast_f16<<<(4194304 + thr - 1) / thr, thr, 0, stream>>>(x, x_h, 4194304);
    k_prep_z<<<262144 / thr, thr, 0, stream>>>(Wih_de, Wz_h);
    k_prep_bias<<<1, 512, 0, stream>>>(bih_en, bhh_en, benc);
    k_prep_bias<<<1, 512, 0, stream>>>(bih_de, bhh_de, bdec);
    // int8 quantization of recurrent weights (per-row scales)
    k_quant<<<512, 128, 0, stream>>>(Whh_en, 512, nullptr, 0, Wq_en, fac_en);
    k_quant<<<512, 128, 0, stream>>>(Wih_de, 1024, Whh_de, 512, Wq_de, fac_de);

    dim3 gFull(32768 / BM, 512 / BN);   // 256 x 4
    dim3 gNarrow(32768 / BM, 1);        // 256 x 1 (N=128)

    // encoder pre-activation: x @ Wih_en^T + (bih_en + bhh_en)
    k_gemm<<<gFull, 256, 0, stream>>>(x_h, Wih_en_h, benc, nullptr, pre_h, 32768, 512, 128);
    // encoder recurrence -> y
    k_rnn<<<64, 512, 0, stream>>>(Wq_en, fac_en, pre_h, act_h);
    // mu_post, logsigma2_post
    k_gemm<<<gFull, 256, 0, stream>>>(act_h, W_mu_h, b_mu, out, nullptr, 32768, 512, 512);
    k_gemm<<<gFull, 256, 0, stream>>>(act_h, W_lv_h, b_lv, out + 16777216, nullptr, 32768, 512, 512);
    // z = eps * exp(lv/2) + mu
    k_z<<<4194304 / thr, thr, 0, stream>>>(out, out + 16777216, eps, z_h, 4194304);
    // decoder pre-activation: z @ Wz^T + (bih_de + bhh_de)
    k_gemm<<<gFull, 256, 0, stream>>>(z_h, Wz_h, bdec, nullptr, pre_h, 32768, 512, 512);
    // decoder recurrence -> outputs (reuse act_h; y is dead)
    k_rnn<<<64, 512, 0, stream>>>(Wq_de, fac_de, pre_h, act_h);
    // output projections
    k_gemm<<<gNarrow, 256, 0, stream>>>(act_h, Wmux_h, b_mux, out + 33554432, nullptr, 32768, 128, 512);
    k_gemm<<<gNarrow, 256, 0, stream>>>(act_h, Wlvx_h, b_lvx, out + 37748736, nullptr, 32768, 128, 512);
}